// Round 1
// baseline (1890.271 us; speedup 1.0000x reference)
//
#include <hip/hip_runtime.h>
#include <math.h>

#define LQ 2000
#define DM 512
#define DI 1024
#define DS 16
#define DTR 32
#define XD 64   // DT_RANK + 2*D_STATE

struct Ptr3 { const float* p[3]; };
struct GB { const float* A; const float* B; float* C; const float* biasM; };

__device__ __forceinline__ float siluf(float x){ return x / (1.0f + __expf(-x)); }
__device__ __forceinline__ float softplusf(float x){ return fmaxf(x, 0.0f) + log1pf(__expf(-fabsf(x))); }
__device__ __forceinline__ float geluf(float x){ return 0.5f * x * (1.0f + erff(x * 0.70710678118654752f)); }
__device__ __forceinline__ float sigmoidf_(float x){ return 1.0f / (1.0f + __expf(-x)); }

// ---------------- index maps for the rate=10 patch re-embedding ----------------
// branch 0 = s2 stream, branch 1 = s3 stream, branch 2 = identity
// idx[b][p] = original position feeding branch-b position p; inv is the inverse.
__global__ void build_idx_kernel(int* __restrict__ idx, int* __restrict__ inv){
  int p = blockIdx.x * blockDim.x + threadIdx.x;
  if (p >= LQ) return;
  // s2 = concat(x0, x1, rev(x2), rev(x3)) pieces, each 500
  int seg = p / 500, m = p % 500, src;
  if (seg == 0){ int r = m/5, c = m%5; src = 20*r + 2*c; }
  else if (seg == 1){ int c = m/100, r = m%100; src = 20*r + 10 + 2*c; }
  else if (seg == 2){ int m0 = 499-m; int r = m0/5, c = m0%5; src = 20*r + 2*c + 1; }
  else { int m0 = 499-m; int c = m0/100, r = m0%100; src = 20*r + 10 + 2*c + 1; }
  idx[p] = src; inv[src] = p;
  // s3 = concat(sub1, sub2), each 1000
  int half = p/1000, q = p%1000, k = q>>1, odd = q&1, r = k/5, c = k%5;
  int s3 = 20*r + 2*c + odd + (half ? 10 : 0);
  idx[LQ+p] = s3; inv[LQ+s3] = p;
  // identity
  idx[2*LQ+p] = p; inv[2*LQ+p] = p;
}

// gather permuted x-half: xp[b][d][l] = xz[d][idx[b][l]]   (d < DI)
__global__ void gather_kernel(const float* __restrict__ xz, const int* __restrict__ idx,
                              float* __restrict__ xp){
  int t = blockIdx.x*256 + threadIdx.x;
  int b = blockIdx.y;
  if (t >= DI*LQ) return;
  int d = t / LQ, l = t % LQ;
  xp[(size_t)b*DI*LQ + t] = xz[d*LQ + idx[b*LQ + l]];
}

// depthwise causal conv (k=4) + bias + silu
__global__ void conv_silu_kernel(const float* __restrict__ xp, Ptr3 cw, Ptr3 cb,
                                 float* __restrict__ xc){
  int t = blockIdx.x*256 + threadIdx.x;
  int b = blockIdx.y;
  if (t >= DI*LQ) return;
  int d = t / LQ, l = t % LQ;
  const float* w = cw.p[b] + d*4;
  const float* xr = xp + (size_t)b*DI*LQ + (size_t)d*LQ;
  float acc = cb.p[b][d];
  #pragma unroll
  for (int tt = 0; tt < 4; ++tt){
    int q = l - 3 + tt;
    if (q >= 0) acc = fmaf(w[tt], xr[q], acc);
  }
  xc[(size_t)b*DI*LQ + t] = siluf(acc);
}

// selective scan: thread = (d, n). 16-lane shfl reduce over n. Fused D*u and *silu(z).
__global__ __launch_bounds__(256) void scan_kernel(
    const float* __restrict__ delta,  // [3][DI][LQ]
    const float* __restrict__ u,      // [3][DI][LQ] (conv output)
    const float* __restrict__ xdt,    // [3][LQ][XD] (l-major x_dbl; cols 32..47=B, 48..63=C)
    const float* __restrict__ xz,     // [2*DI][LQ]  (rows DI.. = z)
    const int* __restrict__ idx,      // [3][LQ]
    Ptr3 Alog, Ptr3 Dp,
    float* __restrict__ o)            // [3][DI][LQ]
{
  int b = blockIdx.y;
  int tid = threadIdx.x;
  int n = tid & 15, dl = tid >> 4;
  int d = blockIdx.x*16 + dl;
  const float* dlt  = delta + (size_t)b*DI*LQ + (size_t)d*LQ;
  const float* uu   = u     + (size_t)b*DI*LQ + (size_t)d*LQ;
  const float* bc   = xdt   + (size_t)b*LQ*XD;
  const int*   ix   = idx   + b*LQ;
  const float* zrow = xz + (size_t)(DI + d)*LQ;
  float* orow = o + (size_t)b*DI*LQ + (size_t)d*LQ;
  float A  = -__expf(Alog.p[b][d*DS + n]);
  float Dv = Dp.p[b][d];
  float h = 0.f;
  for (int l = 0; l < LQ; ++l){
    float dv = dlt[l];
    float uv = uu[l];
    float Bv = bc[l*XD + DTR + n];
    float Cv = bc[l*XD + DTR + DS + n];
    float dA = __expf(dv * A);
    h = fmaf(dA, h, dv * uv * Bv);
    float c = h * Cv;
    c += __shfl_xor(c, 8, 16);
    c += __shfl_xor(c, 4, 16);
    c += __shfl_xor(c, 2, 16);
    c += __shfl_xor(c, 1, 16);
    if (n == 0){
      float y = c + Dv * uv;
      float zv = zrow[ix[l]];
      orow[l] = y * siluf(zv);
    }
  }
}

// out[d][l] = sum_b o_b[d][inv_b[l]]
__global__ void combine_kernel(const float* __restrict__ o, const int* __restrict__ inv,
                               float* __restrict__ out){
  int t = blockIdx.x*256 + threadIdx.x;
  if (t >= DI*LQ) return;
  int d = t / LQ, l = t % LQ;
  float v = o[(size_t)d*LQ + inv[l]]
          + o[(size_t)DI*LQ + (size_t)d*LQ + inv[LQ+l]]
          + o[(size_t)2*DI*LQ + (size_t)d*LQ + l];
  out[t] = v;
}

// per-column (per-l) LayerNorm stats over d; each thread owns one l (coalesced over lanes)
__global__ void colstats_kernel(const float* __restrict__ out, float* __restrict__ mu,
                                float* __restrict__ rstd){
  int l = blockIdx.x*256 + threadIdx.x;
  if (l >= LQ) return;
  float s1 = 0.f, s2 = 0.f;
  for (int d = 0; d < DI; ++d){
    float v = out[(size_t)d*LQ + l];
    s1 += v; s2 = fmaf(v, v, s2);
  }
  float m = s1 * (1.0f/DI);
  float var = s2 * (1.0f/DI) - m*m;
  mu[l] = m;
  rstd[l] = rsqrtf(var + 1e-5f);
}

__device__ __forceinline__ float block_sum(float v, float* sm){
  #pragma unroll
  for (int off = 32; off > 0; off >>= 1) v += __shfl_down(v, off, 64);
  if ((threadIdx.x & 63) == 0) sm[threadIdx.x >> 6] = v;
  __syncthreads();
  float s = 0.f;
  if (threadIdx.x == 0){
    #pragma unroll
    for (int i = 0; i < 4; ++i) s += sm[i];
  }
  return s;
}

// gmean[d] = ln_g[d] * mean_l((out[d,l]-mu[l])*rstd[l]) + ln_b[d]
__global__ void gmean_kernel(const float* __restrict__ out, const float* __restrict__ mu,
                             const float* __restrict__ rstd, const float* __restrict__ g,
                             const float* __restrict__ bta, float* __restrict__ gmean){
  __shared__ float sm[4];
  int d = blockIdx.x;
  float v = 0.f;
  for (int l = threadIdx.x; l < LQ; l += 256)
    v += (out[(size_t)d*LQ + l] - mu[l]) * rstd[l];
  float s = block_sum(v, sm);
  if (threadIdx.x == 0) gmean[d] = g[d] * (s * (1.0f/LQ)) + bta[d];
}

__global__ void g2_kernel(const float* __restrict__ gmean, const float* __restrict__ grw,
                          const float* __restrict__ grb, float* __restrict__ g2){
  __shared__ float sm[4];
  int r = blockIdx.x;
  float v = 0.f;
  for (int d = threadIdx.x; d < DI; d += 256) v = fmaf(gmean[d], grw[r*DI + d], v);
  float s = block_sum(v, sm);
  if (threadIdx.x == 0) g2[r] = geluf(s + grb[r]);
}

__global__ void attn_kernel(const float* __restrict__ g2, const float* __restrict__ csw,
                            const float* __restrict__ csb, float* __restrict__ attn){
  __shared__ float sm[4];
  int d = blockIdx.x;
  float v = 0.f;
  for (int r = threadIdx.x; r < DM; r += 256) v = fmaf(g2[r], csw[d*DM + r], v);
  float s = block_sum(v, sm);
  if (threadIdx.x == 0) attn[d] = sigmoidf_(s + csb[d]);
}

// obp[m] = sum_d ob[d]*opw[m,d]
__global__ void obp_kernel(const float* __restrict__ ob, const float* __restrict__ opw,
                           float* __restrict__ obp){
  __shared__ float sm[4];
  int mI = blockIdx.x;
  float v = 0.f;
  for (int d = threadIdx.x; d < DI; d += 256) v = fmaf(ob[d], opw[mI*DI + d], v);
  float s = block_sum(v, sm);
  if (threadIdx.x == 0) obp[mI] = s;
}

// ---------------- generic fp32 tiled GEMM ----------------
// C[M,N] = A @ B  (+biasM[m]) (+biasN[n]) (EPI==1: softplus)
// AT: A stored (K,M) k-major; BT: B stored (N,K) n-major. ascale: per-k scale on A.
// 3-way batched via blockIdx.z (pass same GB thrice for unbatched).
template<int BM,int BN,int BK,int TM,int TN,bool AT,bool BT,int EPI>
__global__ __launch_bounds__(256) void gemm_kernel(
    int M, int N, int K, GB gb0, GB gb1, GB gb2,
    int lda, int ldb, int ldc,
    const float* __restrict__ ascale, const float* __restrict__ biasN)
{
  GB gb = (blockIdx.z == 0) ? gb0 : ((blockIdx.z == 1) ? gb1 : gb2);
  const float* __restrict__ A = gb.A;
  const float* __restrict__ B = gb.B;
  float* __restrict__ C = gb.C;
  __shared__ __align__(16) float As[BK][BM+4];
  __shared__ __align__(16) float Bs[BK][BN+4];
  const int tid = threadIdx.x;
  const int tx = tid & 15, ty = tid >> 4;
  const int m0 = blockIdx.y * BM, n0 = blockIdx.x * BN;
  float acc[TM][TN];
  #pragma unroll
  for (int i = 0; i < TM; ++i)
    #pragma unroll
    for (int j = 0; j < TN; ++j) acc[i][j] = 0.f;

  for (int k0 = 0; k0 < K; k0 += BK){
    #pragma unroll
    for (int i = 0; i < (BM*BK)/256; ++i){
      int e = tid + i*256;
      int mm, kk;
      if (AT){ mm = e % BM; kk = e / BM; } else { kk = e % BK; mm = e / BK; }
      int gm = m0 + mm, gk = k0 + kk;
      float v = 0.f;
      if (gm < M) v = AT ? A[(size_t)gk*lda + gm] : A[(size_t)gm*lda + gk];
      if (ascale) v *= ascale[gk];
      As[kk][mm] = v;
    }
    #pragma unroll
    for (int i = 0; i < (BK*BN)/256; ++i){
      int e = tid + i*256;
      int nn, kk;
      if (BT){ kk = e % BK; nn = e / BK; } else { nn = e % BN; kk = e / BN; }
      int gn = n0 + nn, gk = k0 + kk;
      float v = 0.f;
      if (gn < N) v = BT ? B[(size_t)gn*ldb + gk] : B[(size_t)gk*ldb + gn];
      Bs[kk][nn] = v;
    }
    __syncthreads();
    #pragma unroll
    for (int kk = 0; kk < BK; ++kk){
      float a[TM], bb[TN];
      #pragma unroll
      for (int i = 0; i < TM; i += 4) *(float4*)&a[i]  = *(const float4*)&As[kk][ty*TM+i];
      #pragma unroll
      for (int j = 0; j < TN; j += 4) *(float4*)&bb[j] = *(const float4*)&Bs[kk][tx*TN+j];
      #pragma unroll
      for (int i = 0; i < TM; ++i)
        #pragma unroll
        for (int j = 0; j < TN; ++j) acc[i][j] = fmaf(a[i], bb[j], acc[i][j]);
    }
    __syncthreads();
  }
  const float* bm = gb.biasM;
  #pragma unroll
  for (int i = 0; i < TM; ++i){
    int gm = m0 + ty*TM + i;
    if (gm >= M) continue;
    float bmv = bm ? bm[gm] : 0.f;
    #pragma unroll
    for (int j = 0; j < TN; ++j){
      int gn = n0 + tx*TN + j;
      if (gn >= N) continue;
      float v = acc[i][j] + bmv;
      if (biasN) v += biasN[gn];
      if (EPI == 1) v = softplusf(v);
      C[(size_t)gm*ldc + gn] = v;
    }
  }
}

extern "C" void kernel_launch(void* const* d_in, const int* in_sizes, int n_in,
                              void* d_out, int out_size, void* d_ws, size_t ws_size,
                              hipStream_t stream){
  const float* hs  = (const float*)d_in[0];
  const float* ipw = (const float*)d_in[1];
  Ptr3 cw    = {{(const float*)d_in[2],  (const float*)d_in[4],  (const float*)d_in[6]}};
  Ptr3 cb    = {{(const float*)d_in[3],  (const float*)d_in[5],  (const float*)d_in[7]}};
  Ptr3 xw    = {{(const float*)d_in[8],  (const float*)d_in[9],  (const float*)d_in[10]}};
  Ptr3 dtw   = {{(const float*)d_in[11], (const float*)d_in[12], (const float*)d_in[13]}};
  Ptr3 dbias = {{(const float*)d_in[14], (const float*)d_in[15], (const float*)d_in[16]}};
  Ptr3 Alog  = {{(const float*)d_in[17], (const float*)d_in[18], (const float*)d_in[19]}};
  Ptr3 Dp    = {{(const float*)d_in[20], (const float*)d_in[21], (const float*)d_in[22]}};
  const float* opw = (const float*)d_in[23];
  const float* lng = (const float*)d_in[24];
  const float* lnb = (const float*)d_in[25];
  const float* grw = (const float*)d_in[26];
  const float* grb = (const float*)d_in[27];
  const float* csw = (const float*)d_in[28];
  const float* csb = (const float*)d_in[29];
  const float* ow  = (const float*)d_in[30];
  const float* ob  = (const float*)d_in[31];
  float* outF = (float*)d_out;

  char* w = (char*)d_ws;
  auto alloc = [&](size_t bytes)->char* {
    char* r = w; w += (bytes + 255) & ~(size_t)255; return r;
  };
  int*   idx   = (int*)  alloc((size_t)3*LQ*4);
  int*   inv   = (int*)  alloc((size_t)3*LQ*4);
  float* xz    = (float*)alloc((size_t)2*DI*LQ*4);
  float* xp    = (float*)alloc((size_t)3*DI*LQ*4);   // reused as o after conv
  float* xc    = (float*)alloc((size_t)3*DI*LQ*4);
  float* xdt   = (float*)alloc((size_t)3*LQ*XD*4);
  float* dlt   = (float*)alloc((size_t)3*DI*LQ*4);
  float* outb  = (float*)alloc((size_t)DI*LQ*4);
  float* mu    = (float*)alloc((size_t)LQ*4);
  float* rstd  = (float*)alloc((size_t)LQ*4);
  float* gmean = (float*)alloc((size_t)DI*4);
  float* g2v   = (float*)alloc((size_t)DM*4);
  float* attn  = (float*)alloc((size_t)DI*4);
  float* obpv  = (float*)alloc((size_t)DM*4);
  float* M2    = (float*)alloc((size_t)DI*DM*4);
  float* o = xp;

  build_idx_kernel<<<(LQ+255)/256, 256, 0, stream>>>(idx, inv);

  // G1: xz[e,l] = sum_d in_proj_w[e,d]*hs[l,d]   (M=2048,N=2000,K=512)
  { GB g = {ipw, hs, xz, nullptr};
    gemm_kernel<128,128,8,8,8,false,true,0>
      <<<dim3((LQ+127)/128, (2*DI+127)/128, 1), 256, 0, stream>>>(
        2*DI, LQ, DM, g, g, g, DM, DM, LQ, nullptr, nullptr); }

  gather_kernel   <<<dim3((DI*LQ+255)/256, 3), 256, 0, stream>>>(xz, idx, xp);
  conv_silu_kernel<<<dim3((DI*LQ+255)/256, 3), 256, 0, stream>>>(xp, cw, cb, xc);

  // G2: xdt[b][l,r] = sum_d x_proj_w_b[r,d]*xc[b][d,l]  (M=2000,N=64,K=1024, AT,BT)
  { GB b0 = {xc + 0*(size_t)DI*LQ, xw.p[0], xdt + 0*(size_t)LQ*XD, nullptr};
    GB b1 = {xc + 1*(size_t)DI*LQ, xw.p[1], xdt + 1*(size_t)LQ*XD, nullptr};
    GB b2 = {xc + 2*(size_t)DI*LQ, xw.p[2], xdt + 2*(size_t)LQ*XD, nullptr};
    gemm_kernel<64,64,16,4,4,true,true,0>
      <<<dim3(1, (LQ+63)/64, 3), 256, 0, stream>>>(
        LQ, XD, DI, b0, b1, b2, LQ, DI, XD, nullptr, nullptr); }

  // G3: delta[b][d,l] = softplus(sum_r dt_proj_w_b[d,r]*xdt[b][l,r] + db[d])  (K=32, BT)
  { GB b0 = {dtw.p[0], xdt + 0*(size_t)LQ*XD, dlt + 0*(size_t)DI*LQ, dbias.p[0]};
    GB b1 = {dtw.p[1], xdt + 1*(size_t)LQ*XD, dlt + 1*(size_t)DI*LQ, dbias.p[1]};
    GB b2 = {dtw.p[2], xdt + 2*(size_t)LQ*XD, dlt + 2*(size_t)DI*LQ, dbias.p[2]};
    gemm_kernel<64,64,16,4,4,false,true,1>
      <<<dim3((LQ+63)/64, DI/64, 3), 256, 0, stream>>>(
        DI, LQ, DTR, b0, b1, b2, DTR, XD, LQ, nullptr, nullptr); }

  scan_kernel<<<dim3(DI/16, 3), 256, 0, stream>>>(dlt, xc, xdt, xz, idx, Alog, Dp, o);

  combine_kernel <<<(DI*LQ+255)/256, 256, 0, stream>>>(o, inv, outb);
  colstats_kernel<<<(LQ+255)/256, 256, 0, stream>>>(outb, mu, rstd);
  gmean_kernel   <<<DI, 256, 0, stream>>>(outb, mu, rstd, lng, lnb, gmean);
  g2_kernel      <<<DM, 256, 0, stream>>>(gmean, grw, grb, g2v);
  attn_kernel    <<<DI, 256, 0, stream>>>(g2v, csw, csb, attn);
  obp_kernel     <<<DM, 256, 0, stream>>>(ob, opw, obpv);

  // M2[d',m] = sum_d ow[d,d']*opw[m,d]  (M=1024,N=512,K=1024, AT,BT)
  { GB g = {ow, opw, M2, nullptr};
    gemm_kernel<64,64,16,4,4,true,true,0>
      <<<dim3(DM/64, DI/64, 1), 256, 0, stream>>>(
        DI, DM, DI, g, g, g, DI, DI, DM, nullptr, nullptr); }

  // final[l,m] = sum_d' attn[d']*outb[d',l]*M2[d',m] + obp[m]  (M=2000,N=512,K=1024, AT)
  { GB g = {outb, M2, outF, nullptr};
    gemm_kernel<64,64,16,4,4,true,false,0>
      <<<dim3(DM/64, (LQ+63)/64, 1), 256, 0, stream>>>(
        LQ, DM, DI, g, g, g, LQ, DM, DM, attn, obpv); }
}

// Round 2
// 1039.578 us; speedup vs baseline: 1.8183x; 1.8183x over previous
//
#include <hip/hip_runtime.h>
#include <math.h>

#define LQ 2000
#define DM 512
#define DI 1024
#define DS 16
#define DTR 32
#define XD 64   // DT_RANK + 2*D_STATE
#define NC 50   // scan chunks
#define CT 40   // steps per chunk (NC*CT == LQ)

struct Ptr3 { const float* p[3]; };
struct GB { const float* A; const float* B; float* C; const float* biasM; };

__device__ __forceinline__ float siluf(float x){ return x / (1.0f + __expf(-x)); }
__device__ __forceinline__ float softplusf(float x){ return fmaxf(x, 0.0f) + log1pf(__expf(-fabsf(x))); }
__device__ __forceinline__ float geluf(float x){ return 0.5f * x * (1.0f + erff(x * 0.70710678118654752f)); }
__device__ __forceinline__ float sigmoidf_(float x){ return 1.0f / (1.0f + __expf(-x)); }

// ---------------- index maps for the rate=10 patch re-embedding ----------------
__global__ void build_idx_kernel(int* __restrict__ idx, int* __restrict__ inv){
  int p = blockIdx.x * blockDim.x + threadIdx.x;
  if (p >= LQ) return;
  int seg = p / 500, m = p % 500, src;
  if (seg == 0){ int r = m/5, c = m%5; src = 20*r + 2*c; }
  else if (seg == 1){ int c = m/100, r = m%100; src = 20*r + 10 + 2*c; }
  else if (seg == 2){ int m0 = 499-m; int r = m0/5, c = m0%5; src = 20*r + 2*c + 1; }
  else { int m0 = 499-m; int c = m0/100, r = m0%100; src = 20*r + 10 + 2*c + 1; }
  idx[p] = src; inv[src] = p;
  int half = p/1000, q = p%1000, k = q>>1, odd = q&1, r = k/5, c = k%5;
  int s3 = 20*r + 2*c + odd + (half ? 10 : 0);
  idx[LQ+p] = s3; inv[LQ+s3] = p;
  idx[2*LQ+p] = p; inv[2*LQ+p] = p;
}

// gather permuted x-half: xp[b][d][l] = xz[d][idx[b][l]]
__global__ void gather_kernel(const float* __restrict__ xz, const int* __restrict__ idx,
                              float* __restrict__ xp){
  int t = blockIdx.x*256 + threadIdx.x;
  int b = blockIdx.y;
  if (t >= DI*LQ) return;
  int d = t / LQ, l = t % LQ;
  xp[(size_t)b*DI*LQ + t] = xz[d*LQ + idx[b*LQ + l]];
}

// depthwise causal conv (k=4) + bias + silu
__global__ void conv_silu_kernel(const float* __restrict__ xp, Ptr3 cw, Ptr3 cb,
                                 float* __restrict__ xc){
  int t = blockIdx.x*256 + threadIdx.x;
  int b = blockIdx.y;
  if (t >= DI*LQ) return;
  int d = t / LQ, l = t % LQ;
  const float* w = cw.p[b] + d*4;
  const float* xr = xp + (size_t)b*DI*LQ + (size_t)d*LQ;
  float acc = cb.p[b][d];
  #pragma unroll
  for (int tt = 0; tt < 4; ++tt){
    int q = l - 3 + tt;
    if (q >= 0) acc = fmaf(w[tt], xr[q], acc);
  }
  xc[(size_t)b*DI*LQ + t] = siluf(acc);
}

// ---------------- chunked parallel selective scan ----------------
// h_l = a_l*h_{l-1} + g_l,  a = exp(delta*A), g = delta*u*B
// Phase 1: per chunk, thread=(b,d,n,c): P = prod a, H = local scan from 0.
__global__ __launch_bounds__(256) void scan_p1_kernel(
    const float* __restrict__ delta, const float* __restrict__ u,
    const float* __restrict__ xdt, Ptr3 Alog,
    float* __restrict__ P, float* __restrict__ H)
{
  int b = blockIdx.z, c = blockIdx.y;
  int tid = threadIdx.x;
  int n = tid & 15, dl = tid >> 4;
  int d = blockIdx.x*16 + dl;
  const float* dlt = delta + ((size_t)b*DI + d)*LQ;
  const float* uu  = u     + ((size_t)b*DI + d)*LQ;
  const float* bc  = xdt   + (size_t)b*LQ*XD;
  float A = -__expf(Alog.p[b][d*DS + n]);
  float h = 0.f, p = 1.f;
  int l0 = c*CT;
  for (int l = l0; l < l0+CT; ++l){
    float dv = dlt[l], uv = uu[l];
    float Bv = bc[l*XD + DTR + n];
    float dA = __expf(dv * A);
    p *= dA;
    h = fmaf(dA, h, dv * uv * Bv);
  }
  size_t off = ((size_t)b*NC + c)*(DI*16) + d*16 + n;
  P[off] = p; H[off] = h;
}

// Phase 2: serial prefix over chunks per (b,d,n); writes h_in per chunk.
__global__ void scan_p2_kernel(const float* __restrict__ P, const float* __restrict__ H,
                               float* __restrict__ Hin){
  int t = blockIdx.x*256 + threadIdx.x;   // [0, 3*DI*16)
  int b = t >> 14, dn = t & 16383;
  float h = 0.f;
  for (int c = 0; c < NC; ++c){
    size_t off = ((size_t)b*NC + c)*(DI*16) + dn;
    Hin[off] = h;
    h = fmaf(P[off], h, H[off]);
  }
}

// Phase 3: recompute local scan seeded with h_in; emit y*silu(z).
__global__ __launch_bounds__(256) void scan_p3_kernel(
    const float* __restrict__ delta, const float* __restrict__ u,
    const float* __restrict__ xdt, const float* __restrict__ xz,
    const int* __restrict__ idx, Ptr3 Alog, Ptr3 Dp,
    const float* __restrict__ Hin, float* __restrict__ o)
{
  int b = blockIdx.z, c = blockIdx.y;
  int tid = threadIdx.x;
  int n = tid & 15, dl = tid >> 4;
  int d = blockIdx.x*16 + dl;
  const float* dlt  = delta + ((size_t)b*DI + d)*LQ;
  const float* uu   = u     + ((size_t)b*DI + d)*LQ;
  const float* bc   = xdt   + (size_t)b*LQ*XD;
  const int*   ix   = idx   + b*LQ;
  const float* zrow = xz + (size_t)(DI + d)*LQ;
  float* orow = o + ((size_t)b*DI + d)*LQ;
  float A  = -__expf(Alog.p[b][d*DS + n]);
  float Dv = Dp.p[b][d];
  float h = Hin[((size_t)b*NC + c)*(DI*16) + d*16 + n];
  int l0 = c*CT;
  for (int l = l0; l < l0+CT; ++l){
    float dv = dlt[l], uv = uu[l];
    float Bv = bc[l*XD + DTR + n];
    float Cv = bc[l*XD + DTR + DS + n];
    float dA = __expf(dv * A);
    h = fmaf(dA, h, dv * uv * Bv);
    float cc = h * Cv;
    cc += __shfl_xor(cc, 8, 16);
    cc += __shfl_xor(cc, 4, 16);
    cc += __shfl_xor(cc, 2, 16);
    cc += __shfl_xor(cc, 1, 16);
    if (n == 0){
      float y = cc + Dv * uv;
      float zv = zrow[ix[l]];
      orow[l] = y * siluf(zv);
    }
  }
}

// out[d][l] = sum_b o_b[d][inv_b[l]]
__global__ void combine_kernel(const float* __restrict__ o, const int* __restrict__ inv,
                               float* __restrict__ out){
  int t = blockIdx.x*256 + threadIdx.x;
  if (t >= DI*LQ) return;
  int d = t / LQ, l = t % LQ;
  float v = o[(size_t)d*LQ + inv[l]]
          + o[(size_t)DI*LQ + (size_t)d*LQ + inv[LQ+l]]
          + o[(size_t)2*DI*LQ + (size_t)d*LQ + l];
  out[t] = v;
}

// per-column LN stats; block handles 16 l's, 16 d-stripes, LDS reduce
__global__ void colstats_kernel(const float* __restrict__ out, float* __restrict__ mu,
                                float* __restrict__ rstd){
  __shared__ float s1s[256], s2s[256];
  int l0 = blockIdx.x * 16;
  int ll = threadIdx.x & 15, stripe = threadIdx.x >> 4;
  float s1 = 0.f, s2 = 0.f;
  for (int d = stripe; d < DI; d += 16){
    float v = out[(size_t)d*LQ + l0 + ll];
    s1 += v; s2 = fmaf(v, v, s2);
  }
  s1s[threadIdx.x] = s1; s2s[threadIdx.x] = s2;
  __syncthreads();
  if (threadIdx.x < 16){
    float a = 0.f, bb = 0.f;
    #pragma unroll
    for (int j = 0; j < 16; ++j){ a += s1s[j*16 + threadIdx.x]; bb += s2s[j*16 + threadIdx.x]; }
    float m = a * (1.0f/DI);
    float var = bb * (1.0f/DI) - m*m;
    mu[l0 + threadIdx.x] = m;
    rstd[l0 + threadIdx.x] = rsqrtf(var + 1e-5f);
  }
}

__device__ __forceinline__ float block_sum(float v, float* sm){
  #pragma unroll
  for (int off = 32; off > 0; off >>= 1) v += __shfl_down(v, off, 64);
  if ((threadIdx.x & 63) == 0) sm[threadIdx.x >> 6] = v;
  __syncthreads();
  float s = 0.f;
  if (threadIdx.x == 0){
    #pragma unroll
    for (int i = 0; i < 4; ++i) s += sm[i];
  }
  return s;
}

__global__ void gmean_kernel(const float* __restrict__ out, const float* __restrict__ mu,
                             const float* __restrict__ rstd, const float* __restrict__ g,
                             const float* __restrict__ bta, float* __restrict__ gmean){
  __shared__ float sm[4];
  int d = blockIdx.x;
  float v = 0.f;
  for (int l = threadIdx.x; l < LQ; l += 256)
    v += (out[(size_t)d*LQ + l] - mu[l]) * rstd[l];
  float s = block_sum(v, sm);
  if (threadIdx.x == 0) gmean[d] = g[d] * (s * (1.0f/LQ)) + bta[d];
}

__global__ void g2_kernel(const float* __restrict__ gmean, const float* __restrict__ grw,
                          const float* __restrict__ grb, float* __restrict__ g2){
  __shared__ float sm[4];
  int r = blockIdx.x;
  float v = 0.f;
  for (int d = threadIdx.x; d < DI; d += 256) v = fmaf(gmean[d], grw[r*DI + d], v);
  float s = block_sum(v, sm);
  if (threadIdx.x == 0) g2[r] = geluf(s + grb[r]);
}

__global__ void attn_kernel(const float* __restrict__ g2, const float* __restrict__ csw,
                            const float* __restrict__ csb, float* __restrict__ attn){
  __shared__ float sm[4];
  int d = blockIdx.x;
  float v = 0.f;
  for (int r = threadIdx.x; r < DM; r += 256) v = fmaf(g2[r], csw[d*DM + r], v);
  float s = block_sum(v, sm);
  if (threadIdx.x == 0) attn[d] = sigmoidf_(s + csb[d]);
}

__global__ void obp_kernel(const float* __restrict__ ob, const float* __restrict__ opw,
                           float* __restrict__ obp){
  __shared__ float sm[4];
  int mI = blockIdx.x;
  float v = 0.f;
  for (int d = threadIdx.x; d < DI; d += 256) v = fmaf(ob[d], opw[mI*DI + d], v);
  float s = block_sum(v, sm);
  if (threadIdx.x == 0) obp[mI] = s;
}

// ---------------- generic fp32 tiled GEMM ----------------
template<int BM,int BN,int BK,int TM,int TN,bool AT,bool BT,int EPI>
__global__ __launch_bounds__(256) void gemm_kernel(
    int M, int N, int K, GB gb0, GB gb1, GB gb2,
    int lda, int ldb, int ldc,
    const float* __restrict__ ascale, const float* __restrict__ biasN)
{
  GB gb = (blockIdx.z == 0) ? gb0 : ((blockIdx.z == 1) ? gb1 : gb2);
  const float* __restrict__ A = gb.A;
  const float* __restrict__ B = gb.B;
  float* __restrict__ C = gb.C;
  __shared__ __align__(16) float As[BK][BM+4];
  __shared__ __align__(16) float Bs[BK][BN+4];
  const int tid = threadIdx.x;
  const int tx = tid & 15, ty = tid >> 4;
  const int m0 = blockIdx.y * BM, n0 = blockIdx.x * BN;
  float acc[TM][TN];
  #pragma unroll
  for (int i = 0; i < TM; ++i)
    #pragma unroll
    for (int j = 0; j < TN; ++j) acc[i][j] = 0.f;

  for (int k0 = 0; k0 < K; k0 += BK){
    #pragma unroll
    for (int i = 0; i < (BM*BK)/256; ++i){
      int e = tid + i*256;
      int mm, kk;
      if (AT){ mm = e % BM; kk = e / BM; } else { kk = e % BK; mm = e / BK; }
      int gm = m0 + mm, gk = k0 + kk;
      float v = 0.f;
      if (gm < M) v = AT ? A[(size_t)gk*lda + gm] : A[(size_t)gm*lda + gk];
      if (ascale) v *= ascale[gk];
      As[kk][mm] = v;
    }
    #pragma unroll
    for (int i = 0; i < (BK*BN)/256; ++i){
      int e = tid + i*256;
      int nn, kk;
      if (BT){ kk = e % BK; nn = e / BK; } else { nn = e % BN; kk = e / BN; }
      int gn = n0 + nn, gk = k0 + kk;
      float v = 0.f;
      if (gn < N) v = BT ? B[(size_t)gn*ldb + gk] : B[(size_t)gk*ldb + gn];
      Bs[kk][nn] = v;
    }
    __syncthreads();
    #pragma unroll
    for (int kk = 0; kk < BK; ++kk){
      float a[TM], bb[TN];
      #pragma unroll
      for (int i = 0; i < TM; i += 4) *(float4*)&a[i]  = *(const float4*)&As[kk][ty*TM+i];
      #pragma unroll
      for (int j = 0; j < TN; j += 4) *(float4*)&bb[j] = *(const float4*)&Bs[kk][tx*TN+j];
      #pragma unroll
      for (int i = 0; i < TM; ++i)
        #pragma unroll
        for (int j = 0; j < TN; ++j) acc[i][j] = fmaf(a[i], bb[j], acc[i][j]);
    }
    __syncthreads();
  }
  const float* bm = gb.biasM;
  #pragma unroll
  for (int i = 0; i < TM; ++i){
    int gm = m0 + ty*TM + i;
    if (gm >= M) continue;
    float bmv = bm ? bm[gm] : 0.f;
    #pragma unroll
    for (int j = 0; j < TN; ++j){
      int gn = n0 + tx*TN + j;
      if (gn >= N) continue;
      float v = acc[i][j] + bmv;
      if (biasN) v += biasN[gn];
      if (EPI == 1) v = softplusf(v);
      C[(size_t)gm*ldc + gn] = v;
    }
  }
}

extern "C" void kernel_launch(void* const* d_in, const int* in_sizes, int n_in,
                              void* d_out, int out_size, void* d_ws, size_t ws_size,
                              hipStream_t stream){
  const float* hs  = (const float*)d_in[0];
  const float* ipw = (const float*)d_in[1];
  Ptr3 cw    = {{(const float*)d_in[2],  (const float*)d_in[4],  (const float*)d_in[6]}};
  Ptr3 cb    = {{(const float*)d_in[3],  (const float*)d_in[5],  (const float*)d_in[7]}};
  Ptr3 xw    = {{(const float*)d_in[8],  (const float*)d_in[9],  (const float*)d_in[10]}};
  Ptr3 dtw   = {{(const float*)d_in[11], (const float*)d_in[12], (const float*)d_in[13]}};
  Ptr3 dbias = {{(const float*)d_in[14], (const float*)d_in[15], (const float*)d_in[16]}};
  Ptr3 Alog  = {{(const float*)d_in[17], (const float*)d_in[18], (const float*)d_in[19]}};
  Ptr3 Dp    = {{(const float*)d_in[20], (const float*)d_in[21], (const float*)d_in[22]}};
  const float* opw = (const float*)d_in[23];
  const float* lng = (const float*)d_in[24];
  const float* lnb = (const float*)d_in[25];
  const float* grw = (const float*)d_in[26];
  const float* grb = (const float*)d_in[27];
  const float* csw = (const float*)d_in[28];
  const float* csb = (const float*)d_in[29];
  const float* ow  = (const float*)d_in[30];
  const float* ob  = (const float*)d_in[31];
  float* outF = (float*)d_out;

  char* w = (char*)d_ws;
  auto alloc = [&](size_t bytes)->char* {
    char* r = w; w += (bytes + 255) & ~(size_t)255; return r;
  };
  int*   idx   = (int*)  alloc((size_t)3*LQ*4);
  int*   inv   = (int*)  alloc((size_t)3*LQ*4);
  float* xz    = (float*)alloc((size_t)2*DI*LQ*4);
  float* xp    = (float*)alloc((size_t)3*DI*LQ*4);   // gather out; then P/H; then o
  float* xc    = (float*)alloc((size_t)3*DI*LQ*4);
  float* xdt   = (float*)alloc((size_t)3*LQ*XD*4);
  float* dlt   = (float*)alloc((size_t)3*DI*LQ*4);
  float* outb  = (float*)alloc((size_t)DI*LQ*4);
  float* mu    = (float*)alloc((size_t)LQ*4);
  float* rstd  = (float*)alloc((size_t)LQ*4);
  float* gmean = (float*)alloc((size_t)DI*4);
  float* g2v   = (float*)alloc((size_t)DM*4);
  float* attn  = (float*)alloc((size_t)DI*4);
  float* obpv  = (float*)alloc((size_t)DM*4);
  float* M2    = (float*)alloc((size_t)DI*DM*4);
  // Aliases (lifetime-disjoint):
  //  - xp content is dead after conv; P,H live p1->p2 in xp's region; o (p3 output)
  //    then overwrites the whole xp region (P,H dead by then).
  //  - Hin lives p2->p3; outb..M2 (10.3 MB contiguous) are only written after p3.
  float* P   = xp;                                   // 3*NC*DI*16 floats = 9.83 MB
  float* H   = xp + (size_t)3*NC*DI*16;              // another 9.83 MB (xp = 24.6 MB)
  float* Hin = outb;                                 // needs 9.83 MB, outb..M2 = 10.3 MB
  float* o   = xp;

  build_idx_kernel<<<(LQ+255)/256, 256, 0, stream>>>(idx, inv);

  // G1: xz[e,l] = sum_d in_proj_w[e,d]*hs[l,d]
  { GB g = {ipw, hs, xz, nullptr};
    gemm_kernel<128,128,8,8,8,false,true,0>
      <<<dim3((LQ+127)/128, (2*DI+127)/128, 1), 256, 0, stream>>>(
        2*DI, LQ, DM, g, g, g, DM, DM, LQ, nullptr, nullptr); }

  gather_kernel   <<<dim3((DI*LQ+255)/256, 3), 256, 0, stream>>>(xz, idx, xp);
  conv_silu_kernel<<<dim3((DI*LQ+255)/256, 3), 256, 0, stream>>>(xp, cw, cb, xc);

  // G2: xdt[b][l,r] = sum_d x_proj_w_b[r,d]*xc[b][d,l]
  { GB b0 = {xc + 0*(size_t)DI*LQ, xw.p[0], xdt + 0*(size_t)LQ*XD, nullptr};
    GB b1 = {xc + 1*(size_t)DI*LQ, xw.p[1], xdt + 1*(size_t)LQ*XD, nullptr};
    GB b2 = {xc + 2*(size_t)DI*LQ, xw.p[2], xdt + 2*(size_t)LQ*XD, nullptr};
    gemm_kernel<64,64,16,4,4,true,true,0>
      <<<dim3(1, (LQ+63)/64, 3), 256, 0, stream>>>(
        LQ, XD, DI, b0, b1, b2, LQ, DI, XD, nullptr, nullptr); }

  // G3: delta[b][d,l] = softplus(dt_proj @ dt + db)
  { GB b0 = {dtw.p[0], xdt + 0*(size_t)LQ*XD, dlt + 0*(size_t)DI*LQ, dbias.p[0]};
    GB b1 = {dtw.p[1], xdt + 1*(size_t)LQ*XD, dlt + 1*(size_t)DI*LQ, dbias.p[1]};
    GB b2 = {dtw.p[2], xdt + 2*(size_t)LQ*XD, dlt + 2*(size_t)DI*LQ, dbias.p[2]};
    gemm_kernel<64,64,16,4,4,false,true,1>
      <<<dim3((LQ+63)/64, DI/64, 3), 256, 0, stream>>>(
        DI, LQ, DTR, b0, b1, b2, DTR, XD, LQ, nullptr, nullptr); }

  // chunked scan
  scan_p1_kernel<<<dim3(DI/16, NC, 3), 256, 0, stream>>>(dlt, xc, xdt, Alog, P, H);
  scan_p2_kernel<<<(3*DI*16)/256, 256, 0, stream>>>(P, H, Hin);
  scan_p3_kernel<<<dim3(DI/16, NC, 3), 256, 0, stream>>>(dlt, xc, xdt, xz, idx,
                                                         Alog, Dp, Hin, o);

  combine_kernel <<<(DI*LQ+255)/256, 256, 0, stream>>>(o, inv, outb);
  colstats_kernel<<<LQ/16, 256, 0, stream>>>(outb, mu, rstd);
  gmean_kernel   <<<DI, 256, 0, stream>>>(outb, mu, rstd, lng, lnb, gmean);
  g2_kernel      <<<DM, 256, 0, stream>>>(gmean, grw, grb, g2v);
  attn_kernel    <<<DI, 256, 0, stream>>>(g2v, csw, csb, attn);
  obp_kernel     <<<DM, 256, 0, stream>>>(ob, opw, obpv);

  // M2[d',m] = sum_d ow[d,d']*opw[m,d]
  { GB g = {ow, opw, M2, nullptr};
    gemm_kernel<64,64,16,4,4,true,true,0>
      <<<dim3(DM/64, DI/64, 1), 256, 0, stream>>>(
        DI, DM, DI, g, g, g, DI, DI, DM, nullptr, nullptr); }

  // final[l,m] = sum_d' attn[d']*outb[d',l]*M2[d',m] + obp[m]
  { GB g = {outb, M2, outF, nullptr};
    gemm_kernel<64,64,16,4,4,true,false,0>
      <<<dim3(DM/64, (LQ+63)/64, 1), 256, 0, stream>>>(
        LQ, DM, DI, g, g, g, LQ, DM, DM, attn, obpv); }
}